// Round 8
// baseline (241.310 us; speedup 1.0000x reference)
//
#include <hip/hip_runtime.h>
#include <hip/hip_bf16.h>

#define NASP 5
#define H1 10
#define SEQ 500
#define EMB 300
#define THREADS 512
#define NKS 10                 // ceil(300/32) k-steps
#define PSTR 52                // proj LDS row stride (floats); 208 B rows, 16B aligned
#define BF_ELEMS (NKS * 4 * 64 * 8)   // 20480 bf16 = 40 KB
#define P2STR 516              // fused-path pooling buffer row stride (floats)
#define ESTR 516               // epilogue pooling buffer row stride (floats)
#define PROJ_OFF 65536         // byte offset of proj region in d_ws (Bf lives below)

typedef float  f32x4  __attribute__((ext_vector_type(4)));
typedef __bf16 bf16x8 __attribute__((ext_vector_type(8)));
typedef short  s16x8  __attribute__((ext_vector_type(8)));
union frag_cast { s16x8 s; bf16x8 b; };

__device__ __host__ inline short f2bf_rne(float x) {
    unsigned u = __builtin_bit_cast(unsigned, x);
    u = u + 0x7FFF + ((u >> 16) & 1);
    return (short)(u >> 16);
}

// ---- prep: W[5][300][10] -> B-fragments Bf[ks][nt][lane][8] (bf16) ----
__global__ void build_bfrag(const float* __restrict__ Wg, short* __restrict__ Bf) {
    int i = blockIdx.x * blockDim.x + threadIdx.x;
    if (i >= BF_ELEMS) return;
    int j    = i & 7;
    int lane = (i >> 3) & 63;
    int nt   = (i >> 9) & 3;
    int ks   = i >> 11;
    int k    = ks * 32 + (lane >> 4) * 8 + j;
    int col  = nt * 16 + (lane & 15);
    float v = 0.f;
    if (k < EMB && col < 50) {
        int a = col / 10, h = col - a * 10;
        v = Wg[a * (EMB * H1) + k * H1 + h];
    }
    Bf[i] = f2bf_rne(v);
}

__device__ inline bf16x8 cvt8(float4 a0, float4 a1) {
    bf16x8 r;
    r[0] = (__bf16)a0.x; r[1] = (__bf16)a0.y; r[2] = (__bf16)a0.z; r[3] = (__bf16)a0.w;
    r[4] = (__bf16)a1.x; r[5] = (__bf16)a1.y; r[6] = (__bf16)a1.z; r[7] = (__bf16)a1.w;
    return r;
}

// =====================================================================================
// Shared phase-1 body: doc x W via MFMA. acc[4][4] per thread.
// =====================================================================================
__device__ inline void phase1_mfma(const float* __restrict__ docB,
                                   const short* __restrict__ Bf,
                                   int wave, int lane, int q, int kg,
                                   f32x4 acc[4][4]) {
    const float* rowp[4];
    #pragma unroll
    for (int i = 0; i < 4; ++i) {
        int row = (wave * 4 + i) * 16 + q;
        row = row < SEQ ? row : SEQ - 1;
        rowp[i] = docB + (size_t)row * EMB + kg * 8;
    }

    #pragma unroll 1
    for (int ks = 0; ks < NKS - 1; ++ks) {
        const int ko = ks * 32;
        frag_cast bfr[4];
        const short* bp = Bf + ((size_t)(ks * 4) * 64 + lane) * 8;
        #pragma unroll
        for (int nt = 0; nt < 4; ++nt)
            bfr[nt].s = *reinterpret_cast<const s16x8*>(bp + nt * 64 * 8);

        float4 s0a = *reinterpret_cast<const float4*>(rowp[0] + ko);
        float4 s0b = *reinterpret_cast<const float4*>(rowp[0] + ko + 4);
        float4 s1a = *reinterpret_cast<const float4*>(rowp[1] + ko);
        float4 s1b = *reinterpret_cast<const float4*>(rowp[1] + ko + 4);
        float4 s2a = *reinterpret_cast<const float4*>(rowp[2] + ko);
        float4 s2b = *reinterpret_cast<const float4*>(rowp[2] + ko + 4);
        float4 s3a = *reinterpret_cast<const float4*>(rowp[3] + ko);
        float4 s3b = *reinterpret_cast<const float4*>(rowp[3] + ko + 4);

        {
            bf16x8 af = cvt8(s0a, s0b);
            #pragma unroll
            for (int nt = 0; nt < 4; ++nt)
                acc[0][nt] = __builtin_amdgcn_mfma_f32_16x16x32_bf16(af, bfr[nt].b, acc[0][nt], 0, 0, 0);
        }
        {
            bf16x8 af = cvt8(s1a, s1b);
            #pragma unroll
            for (int nt = 0; nt < 4; ++nt)
                acc[1][nt] = __builtin_amdgcn_mfma_f32_16x16x32_bf16(af, bfr[nt].b, acc[1][nt], 0, 0, 0);
        }
        {
            bf16x8 af = cvt8(s2a, s2b);
            #pragma unroll
            for (int nt = 0; nt < 4; ++nt)
                acc[2][nt] = __builtin_amdgcn_mfma_f32_16x16x32_bf16(af, bfr[nt].b, acc[2][nt], 0, 0, 0);
        }
        {
            bf16x8 af = cvt8(s3a, s3b);
            #pragma unroll
            for (int nt = 0; nt < 4; ++nt)
                acc[3][nt] = __builtin_amdgcn_mfma_f32_16x16x32_bf16(af, bfr[nt].b, acc[3][nt], 0, 0, 0);
        }
    }
    {   // tail ks = 9: k 288..299 valid; B-frag is zero for k>=300.
        frag_cast bfr[4];
        const short* bp = Bf + ((size_t)(9 * 4) * 64 + lane) * 8;
        #pragma unroll
        for (int nt = 0; nt < 4; ++nt)
            bfr[nt].s = *reinterpret_cast<const s16x8*>(bp + nt * 64 * 8);

        #pragma unroll
        for (int i = 0; i < 4; ++i) {
            const float* ap = rowp[i] + 288;
            float4 a0 = {0.f, 0.f, 0.f, 0.f};
            float4 a1 = {0.f, 0.f, 0.f, 0.f};
            if (kg == 0) { a0 = *reinterpret_cast<const float4*>(ap);
                           a1 = *reinterpret_cast<const float4*>(ap + 4); }
            else if (kg == 1) { a0 = *reinterpret_cast<const float4*>(ap); }
            bf16x8 af = cvt8(a0, a1);
            #pragma unroll
            for (int nt = 0; nt < 4; ++nt)
                acc[i][nt] = __builtin_amdgcn_mfma_f32_16x16x32_bf16(af, bfr[nt].b, acc[i][nt], 0, 0, 0);
        }
    }
}

// =====================================================================================
// Split path kernel 1: GEMM + transpose -> proj[b][512][52] f32
// =====================================================================================
__global__ __launch_bounds__(THREADS, 4)
void arl_gemm(const float* __restrict__ doc,
              const short* __restrict__ Bf,
              float* __restrict__ proj,
              int B) {
    __shared__ float SB[256 * PSTR];

    const int tid  = threadIdx.x;
    const int b    = blockIdx.x;
    const int lane = tid & 63;
    const int wave = tid >> 6;
    const int q    = lane & 15;
    const int kg   = lane >> 4;

    const float* docB = doc + (size_t)b * (SEQ * EMB);

    f32x4 acc[4][4];
    #pragma unroll
    for (int i = 0; i < 4; ++i)
        #pragma unroll
        for (int nt = 0; nt < 4; ++nt)
            acc[i][nt] = (f32x4){0.f, 0.f, 0.f, 0.f};

    phase1_mfma(docB, Bf, wave, lane, q, kg, acc);

    // transpose via LDS (2 halves), store rows to proj (208 B contiguous per thread)
    float* projB = proj + (size_t)b * (512 * 52);

    if (wave < 4) {
        #pragma unroll
        for (int i = 0; i < 4; ++i) {
            int rowL = (wave * 4 + i) * 16 + kg * 4;
            #pragma unroll
            for (int nt = 0; nt < 4; ++nt) {
                int col = nt * 16 + q;
                if (nt < 3 || q < 4) {
                    #pragma unroll
                    for (int r = 0; r < 4; ++r)
                        SB[(rowL + r) * PSTR + col] = acc[i][nt][r];
                }
            }
        }
    }
    __syncthreads();
    if (tid < 256) {
        const float* rp = &SB[tid * PSTR];
        float* op = projB + (size_t)tid * 52;
        #pragma unroll
        for (int j4 = 0; j4 < 13; ++j4)
            *reinterpret_cast<float4*>(op + j4 * 4) =
                *reinterpret_cast<const float4*>(rp + j4 * 4);
    }
    __syncthreads();
    if (wave >= 4) {
        #pragma unroll
        for (int i = 0; i < 4; ++i) {
            int rowL = ((wave - 4) * 4 + i) * 16 + kg * 4;
            #pragma unroll
            for (int nt = 0; nt < 4; ++nt) {
                int col = nt * 16 + q;
                if (nt < 3 || q < 4) {
                    #pragma unroll
                    for (int r = 0; r < 4; ++r)
                        SB[(rowL + r) * PSTR + col] = acc[i][nt][r];
                }
            }
        }
    }
    __syncthreads();
    if (tid >= 256) {
        const float* rp = &SB[(tid - 256) * PSTR];
        float* op = projB + (size_t)tid * 52;     // global row = 256 + (tid-256) = tid
        #pragma unroll
        for (int j4 = 0; j4 < 13; ++j4)
            *reinterpret_cast<float4*>(op + j4 * 4) =
                *reinterpret_cast<const float4*>(rp + j4 * 4);
    }
}

// =====================================================================================
// Split path kernel 2: scores, softmax, pooling. Small LDS -> high occupancy.
// =====================================================================================
__global__ __launch_bounds__(THREADS, 4)
void arl_epi(const float* __restrict__ proj,
             const float* __restrict__ embG,
             float* __restrict__ out,
             int B) {
    __shared__ float SB[13 * ESTR];      // 26832 f = 26.8 KB (pooling buffer / shift overlay)

    const int tid  = threadIdx.x;
    const int b    = blockIdx.x;
    const int lane = tid & 63;
    const int wave = tid >> 6;
    const int s    = tid;
    const bool active = (s < SEQ);

    // load this thread's proj row (rows 500..511 are defined clamp-duplicates)
    float acc2[50];
    {
        const float* rp = proj + ((size_t)b * 512 + s) * 52;
        #pragma unroll
        for (int j4 = 0; j4 < 12; ++j4) {
            float4 v = *reinterpret_cast<const float4*>(rp + j4 * 4);
            acc2[j4 * 4 + 0] = v.x; acc2[j4 * 4 + 1] = v.y;
            acc2[j4 * 4 + 2] = v.z; acc2[j4 * 4 + 3] = v.w;
        }
        float2 v2 = *reinterpret_cast<const float2*>(rp + 48);
        acc2[48] = v2.x; acc2[49] = v2.y;
    }

    float* Ubuf  = &SB[0];       // 5*513 = 2565
    float* W3buf = &SB[2568];    // 5*501 = 2505
    float* red   = &SB[5080];    // 40

    float uu[NASP], vv[NASP], ww[NASP];
    #pragma unroll
    for (int a = 0; a < NASP; ++a) {
        float su = 0.f, sv = 0.f, sw = 0.f;
        #pragma unroll
        for (int h = 0; h < H1; ++h) {
            float pj = acc2[a * 10 + h];
            su = fmaf(pj, embG[a * 30 + h],       su);
            sv = fmaf(pj, embG[a * 30 + 10 + h],  sv);
            sw = fmaf(pj, embG[a * 30 + 20 + h],  sw);
        }
        uu[a] = su; vv[a] = sv; ww[a] = sw;
    }
    if (active) {
        #pragma unroll
        for (int a = 0; a < NASP; ++a) {
            Ubuf[a * 513 + s + 1] = uu[a];
            W3buf[a * 501 + s]    = ww[a];
        }
    }
    if (tid == 0) {
        #pragma unroll
        for (int a = 0; a < NASP; ++a) { Ubuf[a * 513] = 0.f; W3buf[a * 501 + 500] = 0.f; }
    }
    __syncthreads();

    float sc[NASP];
    #pragma unroll
    for (int a = 0; a < NASP; ++a)
        sc[a] = active ? (Ubuf[a * 513 + s] + vv[a] + W3buf[a * 501 + s + 1]) : -1e30f;

    float m[NASP];
    #pragma unroll
    for (int a = 0; a < NASP; ++a) {
        float x = sc[a];
        #pragma unroll
        for (int off = 32; off > 0; off >>= 1) x = fmaxf(x, __shfl_xor(x, off));
        if (lane == 0) red[wave * NASP + a] = x;
    }
    __syncthreads();
    #pragma unroll
    for (int a = 0; a < NASP; ++a) {
        float mm = red[a];
        #pragma unroll
        for (int w2 = 1; w2 < 8; ++w2) mm = fmaxf(mm, red[w2 * NASP + a]);
        m[a] = mm;
    }
    __syncthreads();

    float p[NASP];
    #pragma unroll
    for (int a = 0; a < NASP; ++a) {
        float x = active ? __expf(sc[a] - m[a]) : 0.f;
        p[a] = x;
        float t = x;
        #pragma unroll
        for (int off = 32; off > 0; off >>= 1) t += __shfl_xor(t, off);
        if (lane == 0) red[wave * NASP + a] = t;
    }
    __syncthreads();
    float attnv[NASP];
    #pragma unroll
    for (int a = 0; a < NASP; ++a) {
        float ssum = 0.f;
        #pragma unroll
        for (int w2 = 0; w2 < 8; ++w2) ssum += red[w2 * NASP + a];
        attnv[a] = p[a] / ssum;
    }

    if (active) {
        #pragma unroll
        for (int a = 0; a < NASP; ++a)
            out[((size_t)b * NASP + a) * SEQ + s] = attnv[a];
    }

    // pooling: 4 rounds of <=13 columns; scatter SB[jr][s], gather-reduce
    const int jj = tid >> 4;            // 0..31
    const int g  = tid & 15;
    float* rep_out = out + (size_t)B * NASP * SEQ + (size_t)b * 50;

    #pragma unroll
    for (int rnd = 0; rnd < 4; ++rnd) {
        const int j0 = rnd * 13;
        const int nJ = (rnd < 3) ? 13 : 11;
        __syncthreads();
        #pragma unroll
        for (int jr = 0; jr < 13; ++jr) {
            if (jr < nJ)
                SB[jr * ESTR + s] = acc2[j0 + jr] * attnv[(j0 + jr) / 10];
        }
        __syncthreads();
        if (jj < nJ) {
            const float* rp = &SB[jj * ESTR + g];
            float t = 0.f;
            #pragma unroll
            for (int mi = 0; mi < 32; ++mi) t += rp[mi * 16];
            t += __shfl_xor(t, 1);
            t += __shfl_xor(t, 2);
            t += __shfl_xor(t, 4);
            t += __shfl_xor(t, 8);
            if (g == 0) rep_out[j0 + jj] = t;
        }
    }
}

// =====================================================================================
// Fallback: round-7 fused kernel (used only if ws_size is too small for proj)
// =====================================================================================
__global__ __launch_bounds__(THREADS, 4)
void arl_mfma(const float* __restrict__ doc,
              const short* __restrict__ Bf,
              const float* __restrict__ embG,
              float* __restrict__ out,
              int B) {
    __shared__ float SB[256 * PSTR];

    const int tid  = threadIdx.x;
    const int b    = blockIdx.x;
    const int lane = tid & 63;
    const int wave = tid >> 6;
    const int q    = lane & 15;
    const int kg   = lane >> 4;
    const int s    = tid;
    const bool active = (s < SEQ);

    const float* docB = doc + (size_t)b * (SEQ * EMB);

    f32x4 acc[4][4];
    #pragma unroll
    for (int i = 0; i < 4; ++i)
        #pragma unroll
        for (int nt = 0; nt < 4; ++nt)
            acc[i][nt] = (f32x4){0.f, 0.f, 0.f, 0.f};

    phase1_mfma(docB, Bf, wave, lane, q, kg, acc);

    float acc2[50];
    if (wave < 4) {
        #pragma unroll
        for (int i = 0; i < 4; ++i) {
            int rowL = (wave * 4 + i) * 16 + kg * 4;
            #pragma unroll
            for (int nt = 0; nt < 4; ++nt) {
                int col = nt * 16 + q;
                if (nt < 3 || q < 4) {
                    #pragma unroll
                    for (int r = 0; r < 4; ++r)
                        SB[(rowL + r) * PSTR + col] = acc[i][nt][r];
                }
            }
        }
    }
    __syncthreads();
    if (tid < 256) {
        const float* rp = &SB[tid * PSTR];
        #pragma unroll
        for (int j4 = 0; j4 < 12; ++j4) {
            float4 v = *reinterpret_cast<const float4*>(rp + j4 * 4);
            acc2[j4 * 4 + 0] = v.x; acc2[j4 * 4 + 1] = v.y;
            acc2[j4 * 4 + 2] = v.z; acc2[j4 * 4 + 3] = v.w;
        }
        float2 v2 = *reinterpret_cast<const float2*>(rp + 48);
        acc2[48] = v2.x; acc2[49] = v2.y;
    }
    __syncthreads();
    if (wave >= 4) {
        #pragma unroll
        for (int i = 0; i < 4; ++i) {
            int rowL = ((wave - 4) * 4 + i) * 16 + kg * 4;
            #pragma unroll
            for (int nt = 0; nt < 4; ++nt) {
                int col = nt * 16 + q;
                if (nt < 3 || q < 4) {
                    #pragma unroll
                    for (int r = 0; r < 4; ++r)
                        SB[(rowL + r) * PSTR + col] = acc[i][nt][r];
                }
            }
        }
    }
    __syncthreads();
    if (tid >= 256) {
        const float* rp = &SB[(tid - 256) * PSTR];
        #pragma unroll
        for (int j4 = 0; j4 < 12; ++j4) {
            float4 v = *reinterpret_cast<const float4*>(rp + j4 * 4);
            acc2[j4 * 4 + 0] = v.x; acc2[j4 * 4 + 1] = v.y;
            acc2[j4 * 4 + 2] = v.z; acc2[j4 * 4 + 3] = v.w;
        }
        float2 v2 = *reinterpret_cast<const float2*>(rp + 48);
        acc2[48] = v2.x; acc2[49] = v2.y;
    }
    __syncthreads();

    float* Ubuf  = &SB[160];
    float* W3buf = &SB[2725];
    float* red   = &SB[5232];

    float uu[NASP], vv[NASP], ww[NASP];
    #pragma unroll
    for (int a = 0; a < NASP; ++a) {
        float su = 0.f, sv = 0.f, sw = 0.f;
        #pragma unroll
        for (int h = 0; h < H1; ++h) {
            float pj = acc2[a * 10 + h];
            su = fmaf(pj, embG[a * 30 + h],       su);
            sv = fmaf(pj, embG[a * 30 + 10 + h],  sv);
            sw = fmaf(pj, embG[a * 30 + 20 + h],  sw);
        }
        uu[a] = su; vv[a] = sv; ww[a] = sw;
    }
    if (active) {
        #pragma unroll
        for (int a = 0; a < NASP; ++a) {
            Ubuf[a * 513 + s + 1] = uu[a];
            W3buf[a * 501 + s]    = ww[a];
        }
    }
    if (tid == 0) {
        #pragma unroll
        for (int a = 0; a < NASP; ++a) { Ubuf[a * 513] = 0.f; W3buf[a * 501 + 500] = 0.f; }
    }
    __syncthreads();

    float sc[NASP];
    #pragma unroll
    for (int a = 0; a < NASP; ++a)
        sc[a] = active ? (Ubuf[a * 513 + s] + vv[a] + W3buf[a * 501 + s + 1]) : -1e30f;

    float m[NASP];
    #pragma unroll
    for (int a = 0; a < NASP; ++a) {
        float x = sc[a];
        #pragma unroll
        for (int off = 32; off > 0; off >>= 1) x = fmaxf(x, __shfl_xor(x, off));
        if (lane == 0) red[wave * NASP + a] = x;
    }
    __syncthreads();
    #pragma unroll
    for (int a = 0; a < NASP; ++a) {
        float mm = red[a];
        #pragma unroll
        for (int w2 = 1; w2 < 8; ++w2) mm = fmaxf(mm, red[w2 * NASP + a]);
        m[a] = mm;
    }
    __syncthreads();

    float p[NASP];
    #pragma unroll
    for (int a = 0; a < NASP; ++a) {
        float x = active ? __expf(sc[a] - m[a]) : 0.f;
        p[a] = x;
        float t = x;
        #pragma unroll
        for (int off = 32; off > 0; off >>= 1) t += __shfl_xor(t, off);
        if (lane == 0) red[wave * NASP + a] = t;
    }
    __syncthreads();
    float attnv[NASP];
    #pragma unroll
    for (int a = 0; a < NASP; ++a) {
        float ssum = 0.f;
        #pragma unroll
        for (int w2 = 0; w2 < 8; ++w2) ssum += red[w2 * NASP + a];
        attnv[a] = p[a] / ssum;
    }

    if (active) {
        #pragma unroll
        for (int a = 0; a < NASP; ++a)
            out[((size_t)b * NASP + a) * SEQ + s] = attnv[a];
    }

    const int jj = tid >> 4;
    const int g  = tid & 15;
    float* rep_out = out + (size_t)B * NASP * SEQ + (size_t)b * 50;

    #pragma unroll
    for (int half = 0; half < 2; ++half) {
        __syncthreads();
        #pragma unroll
        for (int jr = 0; jr < 25; ++jr) {
            int j = half * 25 + jr;
            SB[jr * P2STR + s] = acc2[j] * attnv[j / 10];
        }
        __syncthreads();
        if (jj < 25) {
            const float* rp = &SB[jj * P2STR + g];
            float t = 0.f;
            #pragma unroll
            for (int mi = 0; mi < 32; ++mi) t += rp[mi * 16];
            t += __shfl_xor(t, 1);
            t += __shfl_xor(t, 2);
            t += __shfl_xor(t, 4);
            t += __shfl_xor(t, 8);
            if (g == 0) rep_out[half * 25 + jj] = t;
        }
    }
}

extern "C" void kernel_launch(void* const* d_in, const int* in_sizes, int n_in,
                              void* d_out, int out_size, void* d_ws, size_t ws_size,
                              hipStream_t stream) {
    const float* doc = (const float*)d_in[0];
    const float* Wg  = (const float*)d_in[1];
    const float* emb = (const float*)d_in[2];
    float* out = (float*)d_out;
    const int B = in_sizes[0] / (SEQ * EMB);   // 1024

    short* Bf   = (short*)d_ws;                                    // 40 KB at base
    float* proj = (float*)((char*)d_ws + PROJ_OFF);                // [B][512][52] f32
    const size_t needed = (size_t)PROJ_OFF + (size_t)B * 512 * 52 * sizeof(float);

    build_bfrag<<<dim3((BF_ELEMS + 255) / 256), dim3(256), 0, stream>>>(Wg, Bf);

    if (ws_size >= needed) {
        arl_gemm<<<dim3(B), dim3(THREADS), 0, stream>>>(doc, Bf, proj, B);
        arl_epi <<<dim3(B), dim3(THREADS), 0, stream>>>(proj, emb, out, B);
    } else {
        arl_mfma<<<dim3(B), dim3(THREADS), 0, stream>>>(doc, Bf, emb, out, B);
    }
}

// Round 10
// 208.078 us; speedup vs baseline: 1.1597x; 1.1597x over previous
//
#include <hip/hip_runtime.h>
#include <hip/hip_bf16.h>

#define NASP 5
#define H1 10
#define SEQ 500
#define EMB 300
#define THREADS 512
#define NKS 10                 // ceil(300/32) k-steps
#define PSTR 52                // transpose LDS row stride (floats)
#define BF_ELEMS (NKS * 4 * 64 * 8)   // 20480 bf16 = 40 KB
#define P2STR 516              // pooling buffer row stride (floats)
#define LROWS 128              // rows staged per stage
#define LSTR 312               // LDS staging row stride in bf16 (624 B; bank-shift 28 -> <=2-way)
#define STAGEF (LROWS * EMB)   // 38400 floats per stage
#define SBF 19968              // LDS floats: 128*312*2B = 79872 B

typedef float  f32x4  __attribute__((ext_vector_type(4)));
typedef __bf16 bf16x8 __attribute__((ext_vector_type(8)));
typedef short  s16x8  __attribute__((ext_vector_type(8)));
union frag_cast { s16x8 s; bf16x8 b; };

__device__ __host__ inline short f2bf_rne(float x) {
    unsigned u = __builtin_bit_cast(unsigned, x);
    u = u + 0x7FFF + ((u >> 16) & 1);
    return (short)(u >> 16);
}

// ---- prep: W[5][300][10] -> B-fragments Bf[ks][nt][lane][8] (bf16) ----
__global__ void build_bfrag(const float* __restrict__ Wg, short* __restrict__ Bf) {
    int i = blockIdx.x * blockDim.x + threadIdx.x;
    if (i >= BF_ELEMS) return;
    int j    = i & 7;
    int lane = (i >> 3) & 63;
    int nt   = (i >> 9) & 3;
    int ks   = i >> 11;
    int k    = ks * 32 + (lane >> 4) * 8 + j;
    int col  = nt * 16 + (lane & 15);
    float v = 0.f;
    if (k < EMB && col < 50) {
        int a = col / 10, h = col - a * 10;
        v = Wg[a * (EMB * H1) + k * H1 + h];
    }
    Bf[i] = f2bf_rne(v);
}

__global__ __launch_bounds__(THREADS, 4)
void arl_mfma(const float* __restrict__ doc,
              const short* __restrict__ Bf,
              const float* __restrict__ embG,
              float* __restrict__ out,
              int B) {
    __shared__ float SB[SBF];            // 79.9 KB: bf16 doc stage / transpose / epilogue

    const int tid  = threadIdx.x;
    const int b    = blockIdx.x;
    const int lane = tid & 63;
    const int wave = tid >> 6;
    const int q    = lane & 15;
    const int kg   = lane >> 4;
    const int s    = tid;
    const bool active = (s < SEQ);

    short* SBs = reinterpret_cast<short*>(SB);
    const size_t TOTALF = (size_t)B * (SEQ * EMB);

    f32x4 acc[4][4];                     // [stage st][ntile]
    #pragma unroll
    for (int i = 0; i < 4; ++i)
        #pragma unroll
        for (int nt = 0; nt < 4; ++nt)
            acc[i][nt] = (f32x4){0.f, 0.f, 0.f, 0.f};

    // BUGFIX r9->r10: zero the pad columns 300..311 of every staged row. The ks=9
    // tail fragment read (kg=1) spans k=296..303; cols 300..311 are never staged,
    // and uninitialized LDS there can hold Inf/NaN bf16 patterns -> NaN*0 = NaN.
    for (int r = tid; r < LROWS; r += THREADS) {
        *reinterpret_cast<short4*>(SBs + r * LSTR + 300) = (short4){0, 0, 0, 0};
        *reinterpret_cast<short4*>(SBs + r * LSTR + 304) = (short4){0, 0, 0, 0};
        *reinterpret_cast<short4*>(SBs + r * LSTR + 308) = (short4){0, 0, 0, 0};
    }

    // A-fragment LDS base for this thread (local row = wave*16+q, k-offset kg*8 bf16)
    const char* aP = (const char*)SBs + (size_t)(wave * 16 + q) * (LSTR * 2) + kg * 16;

    // ---------------- phase 1: 4 stages of 128 rows; contiguous HBM staging ----------
    #pragma unroll
    for (int st = 0; st < 4; ++st) {
        const size_t gbase = (size_t)b * (SEQ * EMB) + (size_t)st * STAGEF;

        __syncthreads();                 // previous stage's LDS reads complete
        // stage: contiguous 150 KB -> bf16 LDS tile [128][312]
        #pragma unroll
        for (int j = 0; j < 19; ++j) {
            int off = j * 2048 + tid * 4;            // float index within stage
            if (off < STAGEF) {
                float4 v = {0.f, 0.f, 0.f, 0.f};
                if (gbase + off + 4 <= TOTALF)
                    v = *reinterpret_cast<const float4*>(doc + gbase + off);
                int row = off / EMB;                  // const-div
                int col = off - row * EMB;            // 0..296, never crosses row
                short4 w;
                w.x = f2bf_rne(v.x); w.y = f2bf_rne(v.y);
                w.z = f2bf_rne(v.z); w.w = f2bf_rne(v.w);
                *reinterpret_cast<short4*>(SBs + row * LSTR + col) = w;
            }
        }
        __syncthreads();

        // compute: rows (st*8+wave)*16+q from LDS, all K
        #pragma unroll 1
        for (int ks = 0; ks < NKS; ++ks) {
            frag_cast bfr[4];
            const short* bp = Bf + ((size_t)(ks * 4) * 64 + lane) * 8;
            #pragma unroll
            for (int nt = 0; nt < 4; ++nt)
                bfr[nt].s = *reinterpret_cast<const s16x8*>(bp + nt * 64 * 8);

            frag_cast af;
            if (ks < 9 || kg < 2) {
                af.s = *reinterpret_cast<const s16x8*>(aP + ks * 64);
            } else {
                af.s = (s16x8){0, 0, 0, 0, 0, 0, 0, 0};   // k>=304: B is zero anyway
            }
            #pragma unroll
            for (int nt = 0; nt < 4; ++nt)
                acc[st][nt] = __builtin_amdgcn_mfma_f32_16x16x32_bf16(
                    af.b, bfr[nt].b, acc[st][nt], 0, 0, 0);
        }
    }
    __syncthreads();                     // stage-3 LDS reads done before transpose writes

    // ---------------- phase 1.5: transpose acc -> per-thread rows via LDS, 2 halves ----
    // C layout: col = nt*16 + q; row = (st*8+wave)*16 + kg*4 + r.
    float acc2[50];

    #pragma unroll
    for (int st = 0; st < 2; ++st) {     // rows 0..255
        #pragma unroll
        for (int nt = 0; nt < 4; ++nt) {
            int rowL = (st * 8 + wave) * 16 + kg * 4;
            int col = nt * 16 + q;
            if (nt < 3 || q < 4) {
                #pragma unroll
                for (int r = 0; r < 4; ++r)
                    SB[(rowL + r) * PSTR + col] = acc[st][nt][r];
            }
        }
    }
    __syncthreads();
    if (tid < 256) {
        const float* rp = &SB[tid * PSTR];
        #pragma unroll
        for (int j4 = 0; j4 < 12; ++j4) {
            float4 v = *reinterpret_cast<const float4*>(rp + j4 * 4);
            acc2[j4 * 4 + 0] = v.x; acc2[j4 * 4 + 1] = v.y;
            acc2[j4 * 4 + 2] = v.z; acc2[j4 * 4 + 3] = v.w;
        }
        float2 v2 = *reinterpret_cast<const float2*>(rp + 48);
        acc2[48] = v2.x; acc2[49] = v2.y;
    }
    __syncthreads();
    #pragma unroll
    for (int st = 2; st < 4; ++st) {     // rows 256..511
        #pragma unroll
        for (int nt = 0; nt < 4; ++nt) {
            int rowL = ((st - 2) * 8 + wave) * 16 + kg * 4;
            int col = nt * 16 + q;
            if (nt < 3 || q < 4) {
                #pragma unroll
                for (int r = 0; r < 4; ++r)
                    SB[(rowL + r) * PSTR + col] = acc[st][nt][r];
            }
        }
    }
    __syncthreads();
    if (tid >= 256) {
        const float* rp = &SB[(tid - 256) * PSTR];
        #pragma unroll
        for (int j4 = 0; j4 < 12; ++j4) {
            float4 v = *reinterpret_cast<const float4*>(rp + j4 * 4);
            acc2[j4 * 4 + 0] = v.x; acc2[j4 * 4 + 1] = v.y;
            acc2[j4 * 4 + 2] = v.z; acc2[j4 * 4 + 3] = v.w;
        }
        float2 v2 = *reinterpret_cast<const float2*>(rp + 48);
        acc2[48] = v2.x; acc2[49] = v2.y;
    }
    __syncthreads();

    // ---------------- phase 2: scores, softmax (emb via scalar loads), pooling --------
    float* Ubuf  = &SB[160];
    float* W3buf = &SB[2725];
    float* red   = &SB[5232];

    float uu[NASP], vv[NASP], ww[NASP];
    #pragma unroll
    for (int a = 0; a < NASP; ++a) {
        float su = 0.f, sv = 0.f, sw = 0.f;
        #pragma unroll
        for (int h = 0; h < H1; ++h) {
            float pj = acc2[a * 10 + h];
            su = fmaf(pj, embG[a * 30 + h],       su);
            sv = fmaf(pj, embG[a * 30 + 10 + h],  sv);
            sw = fmaf(pj, embG[a * 30 + 20 + h],  sw);
        }
        uu[a] = su; vv[a] = sv; ww[a] = sw;
    }
    if (active) {
        #pragma unroll
        for (int a = 0; a < NASP; ++a) {
            Ubuf[a * 513 + s + 1] = uu[a];
            W3buf[a * 501 + s]    = ww[a];
        }
    }
    if (tid == 0) {
        #pragma unroll
        for (int a = 0; a < NASP; ++a) { Ubuf[a * 513] = 0.f; W3buf[a * 501 + 500] = 0.f; }
    }
    __syncthreads();

    float sc[NASP];
    #pragma unroll
    for (int a = 0; a < NASP; ++a)
        sc[a] = active ? (Ubuf[a * 513 + s] + vv[a] + W3buf[a * 501 + s + 1]) : -1e30f;

    float m[NASP];
    #pragma unroll
    for (int a = 0; a < NASP; ++a) {
        float x = sc[a];
        #pragma unroll
        for (int off = 32; off > 0; off >>= 1) x = fmaxf(x, __shfl_xor(x, off));
        if (lane == 0) red[wave * NASP + a] = x;
    }
    __syncthreads();
    #pragma unroll
    for (int a = 0; a < NASP; ++a) {
        float mm = red[a];
        #pragma unroll
        for (int w2 = 1; w2 < 8; ++w2) mm = fmaxf(mm, red[w2 * NASP + a]);
        m[a] = mm;
    }
    __syncthreads();

    float p[NASP];
    #pragma unroll
    for (int a = 0; a < NASP; ++a) {
        float x = active ? __expf(sc[a] - m[a]) : 0.f;
        p[a] = x;
        float t = x;
        #pragma unroll
        for (int off = 32; off > 0; off >>= 1) t += __shfl_xor(t, off);
        if (lane == 0) red[wave * NASP + a] = t;
    }
    __syncthreads();
    float attnv[NASP];
    #pragma unroll
    for (int a = 0; a < NASP; ++a) {
        float ssum = 0.f;
        #pragma unroll
        for (int w2 = 0; w2 < 8; ++w2) ssum += red[w2 * NASP + a];
        attnv[a] = p[a] / ssum;
    }

    if (active) {
        #pragma unroll
        for (int a = 0; a < NASP; ++a)
            out[((size_t)b * NASP + a) * SEQ + s] = attnv[a];
    }

    // pooling: scatter SB[jr][s], gather-reduce (2 halves of 25 cols)
    const int jj = tid >> 4;
    const int g  = tid & 15;
    float* rep_out = out + (size_t)B * NASP * SEQ + (size_t)b * 50;

    #pragma unroll
    for (int half = 0; half < 2; ++half) {
        __syncthreads();
        #pragma unroll
        for (int jr = 0; jr < 25; ++jr) {
            int j = half * 25 + jr;
            SB[jr * P2STR + s] = acc2[j] * attnv[j / 10];
        }
        __syncthreads();
        if (jj < 25) {
            const float* rp = &SB[jj * P2STR + g];
            float t = 0.f;
            #pragma unroll
            for (int mi = 0; mi < 32; ++mi) t += rp[mi * 16];
            t += __shfl_xor(t, 1);
            t += __shfl_xor(t, 2);
            t += __shfl_xor(t, 4);
            t += __shfl_xor(t, 8);
            if (g == 0) rep_out[half * 25 + jj] = t;
        }
    }
}

extern "C" void kernel_launch(void* const* d_in, const int* in_sizes, int n_in,
                              void* d_out, int out_size, void* d_ws, size_t ws_size,
                              hipStream_t stream) {
    const float* doc = (const float*)d_in[0];
    const float* Wg  = (const float*)d_in[1];
    const float* emb = (const float*)d_in[2];
    float* out = (float*)d_out;
    short* Bf  = (short*)d_ws;                 // 40 KB scratch
    const int B = in_sizes[0] / (SEQ * EMB);   // 1024

    build_bfrag<<<dim3((BF_ELEMS + 255) / 256), dim3(256), 0, stream>>>(Wg, Bf);
    arl_mfma<<<dim3(B), dim3(THREADS), 0, stream>>>(doc, Bf, emb, out, B);
}

// Round 11
// 183.089 us; speedup vs baseline: 1.3180x; 1.1365x over previous
//
#include <hip/hip_runtime.h>
#include <hip/hip_bf16.h>

#define NASP 5
#define H1 10
#define SEQ 500
#define EMB 300
#define THREADS 512
#define NKS 10                 // ceil(300/32) k-steps
#define PSTR 52                // transpose LDS row stride (floats); 208 B rows
#define BF_ELEMS (NKS * 4 * 64 * 8)   // 20480 bf16 = 40 KB
#define P2STR 516              // pooling buffer row stride (floats)

typedef float  f32x4  __attribute__((ext_vector_type(4)));
typedef __bf16 bf16x8 __attribute__((ext_vector_type(8)));
typedef short  s16x8  __attribute__((ext_vector_type(8)));
union frag_cast { s16x8 s; bf16x8 b; };

__device__ __host__ inline short f2bf_rne(float x) {
    unsigned u = __builtin_bit_cast(unsigned, x);
    u = u + 0x7FFF + ((u >> 16) & 1);
    return (short)(u >> 16);
}

// ---- prep: W[5][300][10] -> B-fragments Bf[ks][nt][lane][8] (bf16) ----
__global__ void build_bfrag(const float* __restrict__ Wg, short* __restrict__ Bf) {
    int i = blockIdx.x * blockDim.x + threadIdx.x;
    if (i >= BF_ELEMS) return;
    int j    = i & 7;
    int lane = (i >> 3) & 63;
    int nt   = (i >> 9) & 3;
    int ks   = i >> 11;
    int k    = ks * 32 + (lane >> 4) * 8 + j;
    int col  = nt * 16 + (lane & 15);
    float v = 0.f;
    if (k < EMB && col < 50) {
        int a = col / 10, h = col - a * 10;
        v = Wg[a * (EMB * H1) + k * H1 + h];
    }
    Bf[i] = f2bf_rne(v);
}

__device__ inline bf16x8 cvt8(float4 a0, float4 a1) {
    bf16x8 r;
    r[0] = (__bf16)a0.x; r[1] = (__bf16)a0.y; r[2] = (__bf16)a0.z; r[3] = (__bf16)a0.w;
    r[4] = (__bf16)a1.x; r[5] = (__bf16)a1.y; r[6] = (__bf16)a1.z; r[7] = (__bf16)a1.w;
    return r;
}

__global__ __launch_bounds__(THREADS, 4)
void arl_mfma(const float* __restrict__ doc,
              const short* __restrict__ Bf,
              const float* __restrict__ embG,
              float* __restrict__ out,
              int B) {
    __shared__ float SB[256 * PSTR];     // 53248 B: B-frag LDS (40 KB) / transpose / epilogue

    const int tid  = threadIdx.x;
    const int b    = blockIdx.x;
    const int lane = tid & 63;
    const int wave = tid >> 6;
    const int q    = lane & 15;
    const int kg   = lane >> 4;
    const int s    = tid;
    const bool active = (s < SEQ);

    const float* docB = doc + (size_t)b * (SEQ * EMB);
    short* SBs = reinterpret_cast<short*>(SB);

    // ---- stage B-fragments into LDS once (40960 B = 2560 float4) ----
    {
        const float4* bsrc = reinterpret_cast<const float4*>(Bf);
        float4* bdst = reinterpret_cast<float4*>(SB);
        #pragma unroll
        for (int i = 0; i < 5; ++i)
            bdst[tid + i * THREADS] = bsrc[tid + i * THREADS];
    }

    // per-i row base pointers (row does not depend on ks)
    const float* rowp[4];
    #pragma unroll
    for (int i = 0; i < 4; ++i) {
        int row = (wave * 4 + i) * 16 + q;
        row = row < SEQ ? row : SEQ - 1;
        rowp[i] = docB + (size_t)row * EMB + kg * 8;
    }

    f32x4 acc[4][4];                     // [mtile i][ntile]
    #pragma unroll
    for (int i = 0; i < 4; ++i)
        #pragma unroll
        for (int nt = 0; nt < 4; ++nt)
            acc[i][nt] = (f32x4){0.f, 0.f, 0.f, 0.f};

    __syncthreads();                     // B staged

    // B-fragment LDS base for this lane: chunk (ks*4+nt) at lane*16 B
    const short* bL = SBs + lane * 8;

    // ---------------- phase 1: proj = doc x W via MFMA, k = 0..287 ----------------
    #pragma unroll 1
    for (int ks = 0; ks < NKS - 1; ++ks) {
        const int ko = ks * 32;

        // issue A loads first (VMEM; 8 in flight), B reads from LDS (short latency)
        float4 s0a = *reinterpret_cast<const float4*>(rowp[0] + ko);
        float4 s0b = *reinterpret_cast<const float4*>(rowp[0] + ko + 4);
        float4 s1a = *reinterpret_cast<const float4*>(rowp[1] + ko);
        float4 s1b = *reinterpret_cast<const float4*>(rowp[1] + ko + 4);
        float4 s2a = *reinterpret_cast<const float4*>(rowp[2] + ko);
        float4 s2b = *reinterpret_cast<const float4*>(rowp[2] + ko + 4);
        float4 s3a = *reinterpret_cast<const float4*>(rowp[3] + ko);
        float4 s3b = *reinterpret_cast<const float4*>(rowp[3] + ko + 4);

        frag_cast bfr[4];
        #pragma unroll
        for (int nt = 0; nt < 4; ++nt)
            bfr[nt].s = *reinterpret_cast<const s16x8*>(bL + (size_t)(ks * 4 + nt) * 64 * 8);

        {
            bf16x8 af = cvt8(s0a, s0b);
            #pragma unroll
            for (int nt = 0; nt < 4; ++nt)
                acc[0][nt] = __builtin_amdgcn_mfma_f32_16x16x32_bf16(af, bfr[nt].b, acc[0][nt], 0, 0, 0);
        }
        {
            bf16x8 af = cvt8(s1a, s1b);
            #pragma unroll
            for (int nt = 0; nt < 4; ++nt)
                acc[1][nt] = __builtin_amdgcn_mfma_f32_16x16x32_bf16(af, bfr[nt].b, acc[1][nt], 0, 0, 0);
        }
        {
            bf16x8 af = cvt8(s2a, s2b);
            #pragma unroll
            for (int nt = 0; nt < 4; ++nt)
                acc[2][nt] = __builtin_amdgcn_mfma_f32_16x16x32_bf16(af, bfr[nt].b, acc[2][nt], 0, 0, 0);
        }
        {
            bf16x8 af = cvt8(s3a, s3b);
            #pragma unroll
            for (int nt = 0; nt < 4; ++nt)
                acc[3][nt] = __builtin_amdgcn_mfma_f32_16x16x32_bf16(af, bfr[nt].b, acc[3][nt], 0, 0, 0);
        }
    }
    {   // tail ks = 9: k 288..299 valid; B-frag is zero for k>=300.
        frag_cast bfr[4];
        #pragma unroll
        for (int nt = 0; nt < 4; ++nt)
            bfr[nt].s = *reinterpret_cast<const s16x8*>(bL + (size_t)(9 * 4 + nt) * 64 * 8);

        #pragma unroll
        for (int i = 0; i < 4; ++i) {
            const float* ap = rowp[i] + 288;
            float4 a0 = {0.f, 0.f, 0.f, 0.f};
            float4 a1 = {0.f, 0.f, 0.f, 0.f};
            if (kg == 0) { a0 = *reinterpret_cast<const float4*>(ap);
                           a1 = *reinterpret_cast<const float4*>(ap + 4); }
            else if (kg == 1) { a0 = *reinterpret_cast<const float4*>(ap); }
            bf16x8 af = cvt8(a0, a1);
            #pragma unroll
            for (int nt = 0; nt < 4; ++nt)
                acc[i][nt] = __builtin_amdgcn_mfma_f32_16x16x32_bf16(af, bfr[nt].b, acc[i][nt], 0, 0, 0);
        }
    }
    __syncthreads();                     // all B reads done before transpose overwrites LDS

    // ---------------- phase 1.5: transpose acc -> per-thread rows via LDS, 2 halves ----
    // C layout (verified m89): col = nt*16 + q; row = mtile*16 + kg*4 + r.
    float acc2[50];

    if (wave < 4) {
        #pragma unroll
        for (int i = 0; i < 4; ++i) {
            int rowL = (wave * 4 + i) * 16 + kg * 4;
            #pragma unroll
            for (int nt = 0; nt < 4; ++nt) {
                int col = nt * 16 + q;
                if (nt < 3 || q < 4) {
                    #pragma unroll
                    for (int r = 0; r < 4; ++r)
                        SB[(rowL + r) * PSTR + col] = acc[i][nt][r];
                }
            }
        }
    }
    __syncthreads();
    if (tid < 256) {
        const float* rp = &SB[tid * PSTR];
        #pragma unroll
        for (int j4 = 0; j4 < 12; ++j4) {
            float4 v = *reinterpret_cast<const float4*>(rp + j4 * 4);
            acc2[j4 * 4 + 0] = v.x; acc2[j4 * 4 + 1] = v.y;
            acc2[j4 * 4 + 2] = v.z; acc2[j4 * 4 + 3] = v.w;
        }
        float2 v2 = *reinterpret_cast<const float2*>(rp + 48);
        acc2[48] = v2.x; acc2[49] = v2.y;
    }
    __syncthreads();
    if (wave >= 4) {
        #pragma unroll
        for (int i = 0; i < 4; ++i) {
            int rowL = ((wave - 4) * 4 + i) * 16 + kg * 4;
            #pragma unroll
            for (int nt = 0; nt < 4; ++nt) {
                int col = nt * 16 + q;
                if (nt < 3 || q < 4) {
                    #pragma unroll
                    for (int r = 0; r < 4; ++r)
                        SB[(rowL + r) * PSTR + col] = acc[i][nt][r];
                }
            }
        }
    }
    __syncthreads();
    if (tid >= 256) {
        const float* rp = &SB[(tid - 256) * PSTR];
        #pragma unroll
        for (int j4 = 0; j4 < 12; ++j4) {
            float4 v = *reinterpret_cast<const float4*>(rp + j4 * 4);
            acc2[j4 * 4 + 0] = v.x; acc2[j4 * 4 + 1] = v.y;
            acc2[j4 * 4 + 2] = v.z; acc2[j4 * 4 + 3] = v.w;
        }
        float2 v2 = *reinterpret_cast<const float2*>(rp + 48);
        acc2[48] = v2.x; acc2[49] = v2.y;
    }
    __syncthreads();

    // ---------------- phase 2: scores, softmax (emb via scalar loads), pooling --------
    float* Ubuf  = &SB[160];
    float* W3buf = &SB[2725];
    float* red   = &SB[5232];

    float uu[NASP], vv[NASP], ww[NASP];
    #pragma unroll
    for (int a = 0; a < NASP; ++a) {
        float su = 0.f, sv = 0.f, sw = 0.f;
        #pragma unroll
        for (int h = 0; h < H1; ++h) {
            float pj = acc2[a * 10 + h];
            su = fmaf(pj, embG[a * 30 + h],       su);
            sv = fmaf(pj, embG[a * 30 + 10 + h],  sv);
            sw = fmaf(pj, embG[a * 30 + 20 + h],  sw);
        }
        uu[a] = su; vv[a] = sv; ww[a] = sw;
    }
    if (active) {
        #pragma unroll
        for (int a = 0; a < NASP; ++a) {
            Ubuf[a * 513 + s + 1] = uu[a];
            W3buf[a * 501 + s]    = ww[a];
        }
    }
    if (tid == 0) {
        #pragma unroll
        for (int a = 0; a < NASP; ++a) { Ubuf[a * 513] = 0.f; W3buf[a * 501 + 500] = 0.f; }
    }
    __syncthreads();

    float sc[NASP];
    #pragma unroll
    for (int a = 0; a < NASP; ++a)
        sc[a] = active ? (Ubuf[a * 513 + s] + vv[a] + W3buf[a * 501 + s + 1]) : -1e30f;

    float m[NASP];
    #pragma unroll
    for (int a = 0; a < NASP; ++a) {
        float x = sc[a];
        #pragma unroll
        for (int off = 32; off > 0; off >>= 1) x = fmaxf(x, __shfl_xor(x, off));
        if (lane == 0) red[wave * NASP + a] = x;
    }
    __syncthreads();
    #pragma unroll
    for (int a = 0; a < NASP; ++a) {
        float mm = red[a];
        #pragma unroll
        for (int w2 = 1; w2 < 8; ++w2) mm = fmaxf(mm, red[w2 * NASP + a]);
        m[a] = mm;
    }
    __syncthreads();

    float p[NASP];
    #pragma unroll
    for (int a = 0; a < NASP; ++a) {
        float x = active ? __expf(sc[a] - m[a]) : 0.f;
        p[a] = x;
        float t = x;
        #pragma unroll
        for (int off = 32; off > 0; off >>= 1) t += __shfl_xor(t, off);
        if (lane == 0) red[wave * NASP + a] = t;
    }
    __syncthreads();
    float attnv[NASP];
    #pragma unroll
    for (int a = 0; a < NASP; ++a) {
        float ssum = 0.f;
        #pragma unroll
        for (int w2 = 0; w2 < 8; ++w2) ssum += red[w2 * NASP + a];
        attnv[a] = p[a] / ssum;
    }

    if (active) {
        #pragma unroll
        for (int a = 0; a < NASP; ++a)
            out[((size_t)b * NASP + a) * SEQ + s] = attnv[a];
    }

    // pooling: scatter SB[jr][s], gather-reduce (2 halves of 25 cols)
    const int jj = tid >> 4;
    const int g  = tid & 15;
    float* rep_out = out + (size_t)B * NASP * SEQ + (size_t)b * 50;

    #pragma unroll
    for (int half = 0; half < 2; ++half) {
        __syncthreads();
        #pragma unroll
        for (int jr = 0; jr < 25; ++jr) {
            int j = half * 25 + jr;
            SB[jr * P2STR + s] = acc2[j] * attnv[j / 10];
        }
        __syncthreads();
        if (jj < 25) {
            const float* rp = &SB[jj * P2STR + g];
            float t = 0.f;
            #pragma unroll
            for (int mi = 0; mi < 32; ++mi) t += rp[mi * 16];
            t += __shfl_xor(t, 1);
            t += __shfl_xor(t, 2);
            t += __shfl_xor(t, 4);
            t += __shfl_xor(t, 8);
            if (g == 0) rep_out[half * 25 + jj] = t;
        }
    }
}

extern "C" void kernel_launch(void* const* d_in, const int* in_sizes, int n_in,
                              void* d_out, int out_size, void* d_ws, size_t ws_size,
                              hipStream_t stream) {
    const float* doc = (const float*)d_in[0];
    const float* Wg  = (const float*)d_in[1];
    const float* emb = (const float*)d_in[2];
    float* out = (float*)d_out;
    short* Bf  = (short*)d_ws;                 // 40 KB scratch
    const int B = in_sizes[0] / (SEQ * EMB);   // 1024

    build_bfrag<<<dim3((BF_ELEMS + 255) / 256), dim3(256), 0, stream>>>(Wg, Bf);
    arl_mfma<<<dim3(B), dim3(THREADS), 0, stream>>>(doc, Bf, emb, out, B);
}